// Round 3
// baseline (298.083 us; speedup 1.0000x reference)
//
#include <hip/hip_runtime.h>
#include <hip/hip_bf16.h>
#include <math.h>

#define LQ   15000
#define LS_  15000
#define NB   2
#define ROWS (NB*LQ)   // 30000
#define HGT  100
#define WID  150

typedef __attribute__((ext_vector_type(8))) short bf16x8;
typedef __attribute__((ext_vector_type(4))) float f32x4;

__device__ inline short f2bf(float x) {
    __hip_bfloat16 h = __float2bfloat16(x);
    return *reinterpret_cast<short*>(&h);
}
__device__ inline unsigned pack2bf(float a, float b) {
    return ((unsigned)(unsigned short)f2bf(a)) | (((unsigned)(unsigned short)f2bf(b)) << 16);
}
__device__ inline float bf2f(short s) {
    return __uint_as_float(((unsigned)(unsigned short)s) << 16);
}
__device__ inline float gelu_exact(float x) {
    return 0.5f * x * (1.f + erff(x * 0.70710678118654752440f));
}

// ---- async global->LDS (16B/lane, lane-linear LDS dest) with fallback ----
#if defined(__has_builtin)
#if __has_builtin(__builtin_amdgcn_global_load_lds)
#define HAS_GLL 1
#endif
#endif
#ifndef HAS_GLL
#define HAS_GLL 0
#endif

typedef unsigned int u32;

__device__ __forceinline__ void gld_lds16(const void* g, void* l) {
#if HAS_GLL
    __builtin_amdgcn_global_load_lds(
        (const __attribute__((address_space(1))) u32*)g,
        (__attribute__((address_space(3))) u32*)l,
        16, 0, 0);
#else
    int lane = threadIdx.x & 63;
    *(int4*)((char*)l + lane * 16) = *(const int4*)g;
#endif
}

// counted waits: each stage = exactly 4 global_load_lds per thread.
// WAIT_PREV: oldest stage landed, one younger stage (4 loads) still in flight.
#if HAS_GLL
#define WAIT_PREV() asm volatile("s_waitcnt vmcnt(4)" ::: "memory")
#define WAIT_LAST() asm volatile("s_waitcnt vmcnt(0)" ::: "memory")
#else
#define WAIT_PREV() asm volatile("s_waitcnt vmcnt(0) lgkmcnt(0)" ::: "memory")
#define WAIT_LAST() asm volatile("s_waitcnt vmcnt(0) lgkmcnt(0)" ::: "memory")
#endif

// ================================================================
// fused2<0>: value = mask(LN(src@W1+b1) @ W2 + b2)  (head-major bf16 out)
// fused2<1>: out  = LN2(t + gelu(t@W2+b2)), t = LN1(tgt + A@W1+b1)  (f32 out)
// Block: 64 rows x 256 cols, 4 waves; wave owns 16 full rows.
//
// v3 (resubmit; round-2 bench was an infra failure):
//   counted-vmcnt pipeline (T4). Stage 2 K-chunks ahead; per iter:
//   wait vmcnt(4) -> s_barrier -> ds_read+MFMA -> s_barrier -> stage(k+2).
// No vmcnt(0) drain in the main loop (only at last iter of each phase).
// Epilogue-2 residual kept in f32 registers (tres) instead of T readback.
// LDS = 2*16384 (B dbuf) + 64*264*2 (T) = 66560 B -> 2 blocks/CU.
// ================================================================
template<int MODE>
__global__ __launch_bounds__(256, 2) void fused2(
    const void* __restrict__ Ap,
    const short* __restrict__ W1T, const float* __restrict__ bias1,
    const float* __restrict__ res1,
    const float* __restrict__ g1v, const float* __restrict__ b1v,
    const short* __restrict__ W2T, const float* __restrict__ bias2,
    void* __restrict__ Out,
    const unsigned char* __restrict__ mask,
    const float* __restrict__ g2v, const float* __restrict__ b2v,
    int M)
{
    __shared__ __align__(16) char lds[2 * 16384 + 64 * 264 * 2];  // 66560
    short (*T)[264] = (short(*)[264])(lds + 32768);

    const int tid = threadIdx.x;
    const int bm0 = blockIdx.x * 64;
    const int wave = tid >> 6, lane = tid & 63;
    const int quad = lane >> 4, c = lane & 15;

    // per-lane swizzled B read offset: row c, 16B-slot (quad ^ ((c>>1)&3))
    const int roff = c * 64 + ((quad ^ ((c >> 1) & 3)) << 4);

    // stage one 256x32-short K-chunk of W into buffer `buf` (swizzled source)
    auto stageB = [&](int buf, const short* __restrict__ W, int k0) {
        #pragma unroll
        for (int it = 0; it < 4; ++it) {
            int s = it * 256 + wave * 64 + lane;       // 16B slot 0..1023
            int n = s >> 2;                            // W row 0..255
            int j = (s & 3) ^ ((n >> 1) & 3);          // logical 8-short chunk
            gld_lds16(W + (size_t)n * 256 + k0 + j * 8,
                      lds + buf * 16384 + (it * 256 + wave * 64) * 16);
        }
    };

    // ---------------- prologue: preload A fragments FIRST (keeps stage FIFO clean) ----------------
    int rA = bm0 + wave * 16 + c; if (rA > M - 1) rA = M - 1;
    bf16x8 aReg[8];

    if (MODE == 1) {
        const short* A = (const short*)Ap + (size_t)rA * 256 + quad * 8;
        #pragma unroll
        for (int k = 0; k < 8; ++k) aReg[k] = *(const bf16x8*)(A + k * 32);
    } else {
        const float* A = (const float*)Ap + (size_t)rA * 256 + quad * 8;
        float4 lo[8], hi[8];
        #pragma unroll
        for (int k = 0; k < 8; ++k) {
            lo[k] = *(const float4*)(A + k * 32);
            hi[k] = *(const float4*)(A + k * 32 + 4);
        }
        #pragma unroll
        for (int k = 0; k < 8; ++k) {
            union { int4 i; bf16x8 v; } u;
            u.i.x = pack2bf(lo[k].x, lo[k].y);
            u.i.y = pack2bf(lo[k].z, lo[k].w);
            u.i.z = pack2bf(hi[k].x, hi[k].y);
            u.i.w = pack2bf(hi[k].z, hi[k].w);
            aReg[k] = u.v;
        }
    }

    // stage first two K-chunks (2-deep prefetch)
    stageB(0, W1T, 0);
    stageB(1, W1T, 32);

    f32x4 acc[16];
    #pragma unroll
    for (int t = 0; t < 16; ++t) acc[t] = (f32x4){0.f, 0.f, 0.f, 0.f};

    // ---------------- phase 1: A @ W1, counted-vmcnt pipeline ----------------
    #pragma unroll
    for (int k = 0; k < 8; ++k) {
        if (k < 7) { WAIT_PREV(); } else { WAIT_LAST(); }
        __builtin_amdgcn_s_barrier();
        const char* bb = lds + (k & 1) * 16384 + roff;
        bf16x8 a = aReg[k];
        #pragma unroll
        for (int t = 0; t < 16; ++t) {
            bf16x8 b = *(const bf16x8*)(bb + t * 1024);
            acc[t] = __builtin_amdgcn_mfma_f32_16x16x32_bf16(a, b, acc[t], 0, 0, 0);
        }
        asm volatile("" ::: "memory");
        __builtin_amdgcn_s_barrier();
        if (k < 6) stageB(k & 1, W1T, (k + 2) * 32);
    }

    // issue phase-2 B stages now; latency hides under the LN epilogue
    stageB(0, W2T, 0);
    stageB(1, W2T, 32);

    // ---------------- epilogue 1: (+res) LN -> T (bf16, LDS) + tres (f32, regs) ----------------
    float tres[4][16];   // f32 LN result, lane-local (same mapping in epilogue 2); DCE'd for MODE 0
    {
        const int rb = wave * 16 + quad * 4;
        #pragma unroll
        for (int reg = 0; reg < 4; ++reg) {
            int rloc = rb + reg;
            int rg = bm0 + rloc; int rgl = (rg < M) ? rg : (M - 1);
            float s = 0.f, sq = 0.f;
            float vv[16];
            #pragma unroll
            for (int t = 0; t < 16; ++t) {
                int col = t * 16 + c;
                float v = acc[t][reg] + bias1[col];
                if (MODE == 1) v += res1[(size_t)rgl * 256 + col];
                vv[t] = v; s += v; sq += v * v;
            }
            #pragma unroll
            for (int o = 1; o < 16; o <<= 1) {
                s += __shfl_xor(s, o, 64); sq += __shfl_xor(sq, o, 64);
            }
            float mean = s * (1.f / 256.f);
            float var  = sq * (1.f / 256.f) - mean * mean;
            float rs   = rsqrtf(var + 1e-5f);
            #pragma unroll
            for (int t = 0; t < 16; ++t) {
                int col = t * 16 + c;
                float ln = (vv[t] - mean) * rs * g1v[col] + b1v[col];
                if (MODE == 1) tres[reg][t] = ln;
                T[rloc][col] = f2bf(ln);
            }
        }
    }
    // No barrier needed for T: each wave reads back only rows it wrote (in-order LDS).

    // phase-2 A fragments from T (wave-local rows)
    #pragma unroll
    for (int k = 0; k < 8; ++k)
        aReg[k] = *(const bf16x8*)&T[wave * 16 + c][k * 32 + quad * 8];

    #pragma unroll
    for (int t = 0; t < 16; ++t) acc[t] = (f32x4){0.f, 0.f, 0.f, 0.f};

    // ---------------- phase 2: T @ W2, counted-vmcnt pipeline ----------------
    #pragma unroll
    for (int k = 0; k < 8; ++k) {
        if (k < 7) { WAIT_PREV(); } else { WAIT_LAST(); }
        __builtin_amdgcn_s_barrier();
        const char* bb = lds + (k & 1) * 16384 + roff;
        bf16x8 a = aReg[k];
        #pragma unroll
        for (int t = 0; t < 16; ++t) {
            bf16x8 b = *(const bf16x8*)(bb + t * 1024);
            acc[t] = __builtin_amdgcn_mfma_f32_16x16x32_bf16(a, b, acc[t], 0, 0, 0);
        }
        asm volatile("" ::: "memory");
        __builtin_amdgcn_s_barrier();
        if (k < 6) stageB(k & 1, W2T, (k + 2) * 32);
    }

    // ---------------- epilogue 2 ----------------
    const int rb = wave * 16 + quad * 4;
    if constexpr (MODE == 0) {
        short* O = (short*)Out;
        #pragma unroll
        for (int reg = 0; reg < 4; ++reg) {
            int rloc = rb + reg; int r = bm0 + rloc;
            if (r < M) {
                float mz = mask[r] ? 0.f : 1.f;
                int n = (r >= LS_) ? 1 : 0;
                int sidx = r - n * LS_;
                #pragma unroll
                for (int t = 0; t < 16; ++t) {
                    int col = t * 16 + c; int h = col >> 5, d = col & 31;
                    O[(((size_t)n * 8 + h) * LS_ + sidx) * 32 + d] =
                        f2bf((acc[t][reg] + bias2[col]) * mz);
                }
            }
        }
    } else {
        float* O = (float*)Out;
        #pragma unroll
        for (int reg = 0; reg < 4; ++reg) {
            int r = bm0 + rb + reg;
            float s = 0.f, sq = 0.f;
            float vv[16];
            #pragma unroll
            for (int t = 0; t < 16; ++t) {
                int col = t * 16 + c;
                float v = gelu_exact(acc[t][reg] + bias2[col]) + tres[reg][t];
                vv[t] = v; s += v; sq += v * v;
            }
            #pragma unroll
            for (int o = 1; o < 16; o <<= 1) {
                s += __shfl_xor(s, o, 64); sq += __shfl_xor(sq, o, 64);
            }
            float mean = s * (1.f / 256.f);
            float var  = sq * (1.f / 256.f) - mean * mean;
            float rs   = rsqrtf(var + 1e-5f);
            if (r < M) {
                #pragma unroll
                for (int t = 0; t < 16; ++t) {
                    int col = t * 16 + c;
                    O[(size_t)r * 256 + col] = (vv[t] - mean) * rs * g2v[col] + b2v[col];
                }
            }
        }
    }
}

// ================================================================
// oa_gemm v2: S_oa = (tgt+qpos) @ [W_off|W_attn] + b   (f32 out, [ROWS,96])
// B panel (96x256 bf16 = 48 KB) staged ONCE into padded LDS; A in registers;
// K-loop has ZERO barriers. LDS ~51 KB -> 3 blocks/CU (12 waves).
// ================================================================
__global__ __launch_bounds__(256) void oa_gemm(
    const float* __restrict__ tgt, const float* __restrict__ qpos,
    const short* __restrict__ WToa, const float* __restrict__ b_oa,
    float* __restrict__ S_oa, int M)
{
    __shared__ __align__(16) short Bs[96][264];   // +8 pad: stride 528 B, conflict-free
    __shared__ float sb[96];

    const int tid = threadIdx.x;
    const int bm0 = blockIdx.x * 64;
    const int wave = tid >> 6, lane = tid & 63;
    const int quad = lane >> 4, c = lane & 15;

    if (tid < 96) sb[tid] = b_oa[tid];

    // one-time full-B stage (coalesced int4 reads, padded LDS writes)
    #pragma unroll
    for (int it = 0; it < 12; ++it) {
        int f = it * 256 + tid;            // 8-short chunk id, 96*32 = 3072 total
        int n = f >> 5, ko = (f & 31) * 8;
        *(int4*)&Bs[n][ko] = *(const int4*)&WToa[(size_t)n * 256 + ko];
    }

    // A preload: row r = bm0 + wave*16 + c, packed (tgt+qpos) -> bf16
    int r = bm0 + wave * 16 + c; if (r > M - 1) r = M - 1;
    const float* At = tgt  + (size_t)r * 256 + quad * 8;
    const float* Aq = qpos + (size_t)r * 256 + quad * 8;
    bf16x8 aReg[8];
    #pragma unroll
    for (int k = 0; k < 8; ++k) {
        float4 t0 = *(const float4*)(At + k * 32);
        float4 t1 = *(const float4*)(At + k * 32 + 4);
        float4 q0 = *(const float4*)(Aq + k * 32);
        float4 q1 = *(const float4*)(Aq + k * 32 + 4);
        union { int4 i; bf16x8 v; } u;
        u.i.x = pack2bf(t0.x + q0.x, t0.y + q0.y);
        u.i.y = pack2bf(t0.z + q0.z, t0.w + q0.w);
        u.i.z = pack2bf(t1.x + q1.x, t1.y + q1.y);
        u.i.w = pack2bf(t1.z + q1.z, t1.w + q1.w);
        aReg[k] = u.v;
    }

    f32x4 acc[6];
    #pragma unroll
    for (int t = 0; t < 6; ++t) acc[t] = (f32x4){0.f, 0.f, 0.f, 0.f};

    __syncthreads();   // B fully staged (one-time full drain is fine)

    // barrier-free K-loop
    #pragma unroll
    for (int k = 0; k < 8; ++k) {
        bf16x8 a = aReg[k];
        #pragma unroll
        for (int t = 0; t < 6; ++t) {
            bf16x8 b = *(const bf16x8*)&Bs[t * 16 + c][k * 32 + quad * 8];
            acc[t] = __builtin_amdgcn_mfma_f32_16x16x32_bf16(a, b, acc[t], 0, 0, 0);
        }
    }

    const int rb = wave * 16 + quad * 4;
    #pragma unroll
    for (int reg = 0; reg < 4; ++reg) {
        int rr = bm0 + rb + reg;
        if (rr < M) {
            #pragma unroll
            for (int t = 0; t < 6; ++t)
                S_oa[(size_t)rr * 96 + t * 16 + c] = acc[t][reg] + sb[t * 16 + c];
        }
    }
}

// ================================================================
// deform_sample: 8 lanes per (r,h), 4 channels/lane; 7500 blocks for TLP.
// (unchanged)
// ================================================================
__global__ __launch_bounds__(256) void deform_sample(
    const short* __restrict__ value,   // [NB][8][LS_][32] bf16, head-major
    const float* __restrict__ S_oa,    // [ROWS, 96]
    const float* __restrict__ refp,    // [ROWS, 2]
    short* __restrict__ out)           // [ROWS, 256] bf16
{
    int grp = blockIdx.x * 32 + (threadIdx.x >> 3);
    int c4  = threadIdx.x & 7;
    int h = grp & 7;
    int r = grp >> 3;
    int n = (r >= LS_) ? 1 : 0;

    const float* row = S_oa + (size_t)r * 96;
    float rx = refp[(size_t)r * 2 + 0], ry = refp[(size_t)r * 2 + 1];
    float4 oA = *(const float4*)&row[h * 8];
    float4 oB = *(const float4*)&row[h * 8 + 4];
    float4 lg = *(const float4*)&row[64 + h * 4];

    float mx = fmaxf(fmaxf(lg.x, lg.y), fmaxf(lg.z, lg.w));
    float e0 = expf(lg.x - mx), e1 = expf(lg.y - mx), e2 = expf(lg.z - mx), e3 = expf(lg.w - mx);
    float inv = 1.f / (e0 + e1 + e2 + e3);
    float aw[4] = {e0 * inv, e1 * inv, e2 * inv, e3 * inv};
    float ox[4] = {oA.x, oA.z, oB.x, oB.z};
    float oy[4] = {oA.y, oA.w, oB.y, oB.w};

    const short* vb = value + (((size_t)n * 8 + h) * LS_) * 32 + c4 * 4;
    float a0 = 0.f, a1 = 0.f, a2 = 0.f, a3 = 0.f;

    #pragma unroll
    for (int p = 0; p < 4; ++p) {
        float x = rx * (float)WID + ox[p] - 0.5f;
        float y = ry * (float)HGT + oy[p] - 0.5f;
        float x0f = floorf(x), y0f = floorf(y);
        float lx = x - x0f, ly = y - y0f;
        int x0 = (int)x0f, y0 = (int)y0f;
        int x1 = x0 + 1, y1 = y0 + 1;
        bool vx0 = (x0 >= 0) & (x0 < WID), vx1 = (x1 >= 0) & (x1 < WID);
        bool vy0 = (y0 >= 0) & (y0 < HGT), vy1 = (y1 >= 0) & (y1 < HGT);
        float w00 = (vx0 & vy0) ? (1.f - lx) * (1.f - ly) * aw[p] : 0.f;
        float w10 = (vx1 & vy0) ? lx * (1.f - ly) * aw[p] : 0.f;
        float w01 = (vx0 & vy1) ? (1.f - lx) * ly * aw[p] : 0.f;
        float w11 = (vx1 & vy1) ? lx * ly * aw[p] : 0.f;
        int xc0 = min(max(x0, 0), WID - 1), xc1 = min(max(x1, 0), WID - 1);
        int yc0 = min(max(y0, 0), HGT - 1), yc1 = min(max(y1, 0), HGT - 1);
        int2 v00 = *(const int2*)&vb[(size_t)(yc0 * WID + xc0) * 32];
        int2 v10 = *(const int2*)&vb[(size_t)(yc0 * WID + xc1) * 32];
        int2 v01 = *(const int2*)&vb[(size_t)(yc1 * WID + xc0) * 32];
        int2 v11 = *(const int2*)&vb[(size_t)(yc1 * WID + xc1) * 32];
        a0 += w00 * __uint_as_float(((unsigned)v00.x) << 16)
            + w10 * __uint_as_float(((unsigned)v10.x) << 16)
            + w01 * __uint_as_float(((unsigned)v01.x) << 16)
            + w11 * __uint_as_float(((unsigned)v11.x) << 16);
        a1 += w00 * __uint_as_float(v00.x & 0xffff0000u)
            + w10 * __uint_as_float(v10.x & 0xffff0000u)
            + w01 * __uint_as_float(v01.x & 0xffff0000u)
            + w11 * __uint_as_float(v11.x & 0xffff0000u);
        a2 += w00 * __uint_as_float(((unsigned)v00.y) << 16)
            + w10 * __uint_as_float(((unsigned)v10.y) << 16)
            + w01 * __uint_as_float(((unsigned)v01.y) << 16)
            + w11 * __uint_as_float(((unsigned)v11.y) << 16);
        a3 += w00 * __uint_as_float(v00.y & 0xffff0000u)
            + w10 * __uint_as_float(v10.y & 0xffff0000u)
            + w01 * __uint_as_float(v01.y & 0xffff0000u)
            + w11 * __uint_as_float(v11.y & 0xffff0000u);
    }
    int2 o;
    o.x = pack2bf(a0, a1);
    o.y = pack2bf(a2, a3);
    *(int2*)&out[(size_t)r * 256 + h * 32 + c4 * 4] = o;
}

// ================================================================
// prep_all: all weight prep in one dispatch (401 blocks)  (unchanged)
// ================================================================
__global__ __launch_bounds__(256) void prep_all(
    const float* __restrict__ W_dsa, const float* __restrict__ W_val,
    const float* __restrict__ W_ff,  const float* __restrict__ W_out,
    const float* __restrict__ W_csa, const float* __restrict__ b_out,
    const float* __restrict__ b_csa, const float* __restrict__ W_off,
    const float* __restrict__ W_attn, const float* __restrict__ b_off,
    const float* __restrict__ b_attn,
    short* __restrict__ WT_dsa, short* __restrict__ WT_val, short* __restrict__ WT_ff,
    short* __restrict__ WT_c, float* __restrict__ bc,
    short* __restrict__ WT_oa, float* __restrict__ b_oa)
{
    __shared__ float tile[64][65];
    const int b = blockIdx.x, tid = threadIdx.x;
    if (b < 48) {
        const float* W = (b < 16) ? W_dsa : (b < 32) ? W_val : W_ff;
        short* WT = (b < 16) ? WT_dsa : (b < 32) ? WT_val : WT_ff;
        int t = b & 15; int bx = (t & 3) * 64, by = (t >> 2) * 64;
        #pragma unroll
        for (int it = 0; it < 4; ++it) {
            int f = it * 256 + tid; int i = f >> 4; int j = (f & 15) * 4;
            float4 v = *(const float4*)&W[(size_t)(by + i) * 256 + bx + j];
            tile[i][j] = v.x; tile[i][j + 1] = v.y; tile[i][j + 2] = v.z; tile[i][j + 3] = v.w;
        }
        __syncthreads();
        #pragma unroll
        for (int it = 0; it < 16; ++it) {
            int f = it * 256 + tid; int nl = f >> 6; int kl = f & 63;
            WT[(size_t)(bx + nl) * 256 + by + kl] = f2bf(tile[kl][nl]);
        }
    } else if (b < 304) {
        int k = b - 48, n = tid;
        float s = 0.f;
        #pragma unroll 8
        for (int j = 0; j < 256; ++j)
            s = fmaf(W_out[(size_t)k * 256 + j], W_csa[(size_t)j * 256 + n], s);
        WT_c[(size_t)n * 256 + k] = f2bf(s);
    } else if (b == 304) {
        int j = tid;
        float s = b_csa[j];
        #pragma unroll 8
        for (int k = 0; k < 256; ++k)
            s = fmaf(b_out[k], W_csa[(size_t)k * 256 + j], s);
        bc[j] = s;
    } else {
        int j = b - 305, k = tid;
        float v = (j < 64) ? W_off[(size_t)k * 64 + j] : W_attn[(size_t)k * 32 + (j - 64)];
        WT_oa[(size_t)j * 256 + k] = f2bf(v);
        if (k == 0) b_oa[j] = (j < 64) ? b_off[j] : b_attn[j - 64];
    }
}

// ================= launcher =================
extern "C" void kernel_launch(void* const* d_in, const int* in_sizes, int n_in,
                              void* d_out, int out_size, void* d_ws, size_t ws_size,
                              hipStream_t stream)
{
    const float* tgt       = (const float*)d_in[0];
    const float* query_pos = (const float*)d_in[1];
    const float* refp      = (const float*)d_in[4];
    const float* src       = (const float*)d_in[6];
    const unsigned char* mask = (const unsigned char*)d_in[9];
    const float* W_dsa  = (const float*)d_in[10]; const float* b_dsa  = (const float*)d_in[11];
    const float* g_nds  = (const float*)d_in[12]; const float* b_nds  = (const float*)d_in[13];
    const float* W_off  = (const float*)d_in[14]; const float* b_off  = (const float*)d_in[15];
    const float* W_attn = (const float*)d_in[16]; const float* b_attn = (const float*)d_in[17];
    const float* W_val  = (const float*)d_in[18]; const float* b_val  = (const float*)d_in[19];
    const float* W_out  = (const float*)d_in[20]; const float* b_out  = (const float*)d_in[21];
    const float* W_csa  = (const float*)d_in[22]; const float* b_csa  = (const float*)d_in[23];
    const float* g_n1   = (const float*)d_in[24]; const float* b_n1   = (const float*)d_in[25];
    const float* W_ff   = (const float*)d_in[26]; const float* b_ff   = (const float*)d_in[27];
    const float* g_n3   = (const float*)d_in[28]; const float* b_n3   = (const float*)d_in[29];
    float* out = (float*)d_out;

    short* attn_out = (short*)d_ws;                       // [30000*256] bf16
    short* value    = attn_out + (size_t)ROWS * 256;      // [30000*256] bf16 head-major
    float* S_oa     = (float*)(value + (size_t)ROWS * 256); // [30000*96] f32
    short* WT_dsa   = (short*)(S_oa + (size_t)ROWS * 96);
    short* WT_val   = WT_dsa + 65536;
    short* WT_ff    = WT_val + 65536;
    short* WT_c     = WT_ff + 65536;
    short* WT_oa    = WT_c + 65536;                       // 96*256
    float* bc       = (float*)(WT_oa + 96 * 256);
    float* b_oa     = bc + 256;

    dim3 blk(256);
    const int GB = (ROWS + 63) / 64;   // 469

    prep_all<<<401, blk, 0, stream>>>(
        W_dsa, W_val, W_ff, W_out, W_csa, b_out, b_csa, W_off, W_attn, b_off, b_attn,
        WT_dsa, WT_val, WT_ff, WT_c, bc, WT_oa, b_oa);

    // S_oa = (tgt+qpos)@[W_off|W_attn]+b  (independent of value path)
    oa_gemm<<<GB, blk, 0, stream>>>(tgt, query_pos, WT_oa, b_oa, S_oa, ROWS);

    // value = mask(LN(src@W_dsa+b_dsa) @ W_val + b_val), head-major
    fused2<0><<<GB, blk, 0, stream>>>(
        src, WT_dsa, b_dsa, nullptr, g_nds, b_nds,
        WT_val, b_val, value, mask, nullptr, nullptr, ROWS);

    // attn_out = deform-sample (softmax fused), high-TLP grid
    deform_sample<<<ROWS * 8 / 32, blk, 0, stream>>>(value, S_oa, refp, attn_out);

    // out = LN3(t + gelu(t@W_ff+b_ff)), t = LN1(tgt + attn_out@Wc+bc)
    fused2<1><<<GB, blk, 0, stream>>>(
        attn_out, WT_c, bc, tgt, g_n1, b_n1,
        WT_ff, b_ff, out, nullptr, g_n3, b_n3, ROWS);
}

// Round 5
// 293.187 us; speedup vs baseline: 1.0167x; 1.0167x over previous
//
#include <hip/hip_runtime.h>
#include <hip/hip_bf16.h>
#include <math.h>

#define LQ   15000
#define LS_  15000
#define NB   2
#define ROWS (NB*LQ)   // 30000
#define HGT  100
#define WID  150

typedef __attribute__((ext_vector_type(8))) short bf16x8;
typedef __attribute__((ext_vector_type(4))) float f32x4;

__device__ inline short f2bf(float x) {
    __hip_bfloat16 h = __float2bfloat16(x);
    return *reinterpret_cast<short*>(&h);
}
__device__ inline unsigned pack2bf(float a, float b) {
    return ((unsigned)(unsigned short)f2bf(a)) | (((unsigned)(unsigned short)f2bf(b)) << 16);
}
__device__ inline float bf2f(short s) {
    return __uint_as_float(((unsigned)(unsigned short)s) << 16);
}
__device__ inline float gelu_exact(float x) {
    return 0.5f * x * (1.f + erff(x * 0.70710678118654752440f));
}

// ---- async global->LDS (16B/lane, lane-linear LDS dest) with fallback ----
#if defined(__has_builtin)
#if __has_builtin(__builtin_amdgcn_global_load_lds)
#define HAS_GLL 1
#endif
#endif
#ifndef HAS_GLL
#define HAS_GLL 0
#endif

typedef unsigned int u32;

__device__ __forceinline__ void gld_lds16(const void* g, void* l) {
#if HAS_GLL
    __builtin_amdgcn_global_load_lds(
        (const __attribute__((address_space(1))) u32*)g,
        (__attribute__((address_space(3))) u32*)l,
        16, 0, 0);
#else
    int lane = threadIdx.x & 63;
    *(int4*)((char*)l + lane * 16) = *(const int4*)g;
#endif
}

// ================================================================
// fused2<0>: value = mask(LN(src@W1+b1) @ W2 + b2)  (head-major bf16 out)
// fused2<1>: out  = LN2(t + gelu(t@W2+b2)), t = LN1(tgt + A@W1+b1)  (f32 out)
//
// v5 (bisect of v4's failure): KEEP the 512-thread / 8-wave split-N structure
// (the occupancy lever), DROP all exotic sync. Every barrier is a plain
// __syncthreads(); K-loop = 1 barrier/iter, stage-at-top (round-1-proven shape).
// Zero inline asm. If this passes, sync was v4's bug; if not, structure is.
//
// Wave (p,h): rows [p*16,+16) x cols [h*128,+128). acc = 8 x f32x4.
// LDS = 2*16384 (B dbuf) + 64*264*2 (T) + 1024 (PR) = 68608 B -> 2 blocks/CU,
// 16 waves/CU (vs 8 in v3).
// ================================================================
template<int MODE>
__global__ __launch_bounds__(512, 4) void fused2(
    const void* __restrict__ Ap,
    const short* __restrict__ W1T, const float* __restrict__ bias1,
    const float* __restrict__ res1,
    const float* __restrict__ g1v, const float* __restrict__ b1v,
    const short* __restrict__ W2T, const float* __restrict__ bias2,
    void* __restrict__ Out,
    const unsigned char* __restrict__ mask,
    const float* __restrict__ g2v, const float* __restrict__ b2v,
    int M)
{
    __shared__ __align__(16) char lds[2 * 16384 + 64 * 264 * 2 + 1024];  // 68608
    short (*T)[264] = (short(*)[264])(lds + 32768);
    float (*PR)[2][2] = (float(*)[2][2])(lds + 66560);   // [row 0..63][half][{s,sq}]

    const int tid = threadIdx.x;
    const int bm0 = blockIdx.x * 64;
    const int wave = tid >> 6, lane = tid & 63;
    const int quad = lane >> 4, c = lane & 15;
    const int p = wave >> 1, h = wave & 1;       // row-pair, N-half
    const int rowbase = p * 16;

    // per-lane swizzled B read offset: row c, 16B-slot (quad ^ ((c>>1)&3))
    const int roff = c * 64 + ((quad ^ ((c >> 1) & 3)) << 4);

    // stage one 256x32-short K-chunk of W into buffer `buf` (swizzled source)
    auto stageB = [&](int buf, const short* __restrict__ W, int k0) {
        #pragma unroll
        for (int it = 0; it < 2; ++it) {
            int s = it * 512 + wave * 64 + lane;       // 16B slot 0..1023
            int n = s >> 2;                            // W row 0..255
            int j = (s & 3) ^ ((n >> 1) & 3);          // logical 8-short chunk
            gld_lds16(W + (size_t)n * 256 + k0 + j * 8,
                      lds + buf * 16384 + (it * 512 + wave * 64) * 16);
        }
    };

    // ---------------- prologue: A fragments + first B chunk ----------------
    int rA = bm0 + rowbase + c; if (rA > M - 1) rA = M - 1;
    bf16x8 aReg[8];

    if (MODE == 1) {
        const short* A = (const short*)Ap + (size_t)rA * 256 + quad * 8;
        #pragma unroll
        for (int k = 0; k < 8; ++k) aReg[k] = *(const bf16x8*)(A + k * 32);
    } else {
        const float* A = (const float*)Ap + (size_t)rA * 256 + quad * 8;
        #pragma unroll
        for (int k = 0; k < 8; ++k) {
            float4 lo = *(const float4*)(A + k * 32);
            float4 hi = *(const float4*)(A + k * 32 + 4);
            union { int4 i; bf16x8 v; } u;
            u.i.x = pack2bf(lo.x, lo.y);
            u.i.y = pack2bf(lo.z, lo.w);
            u.i.z = pack2bf(hi.x, hi.y);
            u.i.w = pack2bf(hi.z, hi.w);
            aReg[k] = u.v;
        }
    }

    stageB(0, W1T, 0);

    f32x4 acc[8];
    #pragma unroll
    for (int t = 0; t < 8; ++t) acc[t] = (f32x4){0.f, 0.f, 0.f, 0.f};

    __syncthreads();   // chunk0 landed

    // ---------------- phase 1: A @ W1 (stage-at-top, 1 barrier/iter) ----------------
    #pragma unroll
    for (int k = 0; k < 8; ++k) {
        if (k < 7) stageB((k + 1) & 1, W1T, (k + 1) * 32);
        const char* bb = lds + (k & 1) * 16384 + h * 8192 + roff;
        bf16x8 a = aReg[k];
        #pragma unroll
        for (int t = 0; t < 8; ++t) {
            bf16x8 b = *(const bf16x8*)(bb + t * 1024);
            acc[t] = __builtin_amdgcn_mfma_f32_16x16x32_bf16(a, b, acc[t], 0, 0, 0);
        }
        __syncthreads();
    }

    // issue phase-2 first B stage; drained by epilogue-1's first __syncthreads
    stageB(0, W2T, 0);

    // ---------------- epilogue 1: (+res) LN -> T, cross-half via PR ----------------
    {
        float vv[4][8];
        #pragma unroll
        for (int reg = 0; reg < 4; ++reg) {
            int rloc = rowbase + quad * 4 + reg;
            int rg = bm0 + rloc; int rgl = (rg < M) ? rg : (M - 1);
            float s = 0.f, sq = 0.f;
            #pragma unroll
            for (int t = 0; t < 8; ++t) {
                int col = h * 128 + t * 16 + c;
                float v = acc[t][reg] + bias1[col];
                if (MODE == 1) v += res1[(size_t)rgl * 256 + col];
                vv[reg][t] = v; s += v; sq += v * v;
            }
            #pragma unroll
            for (int o = 1; o < 16; o <<= 1) {
                s += __shfl_xor(s, o, 64); sq += __shfl_xor(sq, o, 64);
            }
            if (c == 0) { PR[rloc][h][0] = s; PR[rloc][h][1] = sq; }
        }
        __syncthreads();   // PR complete
        #pragma unroll
        for (int reg = 0; reg < 4; ++reg) {
            int rloc = rowbase + quad * 4 + reg;
            float s  = PR[rloc][0][0] + PR[rloc][1][0];
            float sq = PR[rloc][0][1] + PR[rloc][1][1];
            float mean = s * (1.f / 256.f);
            float var  = sq * (1.f / 256.f) - mean * mean;
            float rs   = rsqrtf(var + 1e-5f);
            #pragma unroll
            for (int t = 0; t < 8; ++t) {
                int col = h * 128 + t * 16 + c;
                T[rloc][col] = f2bf((vv[reg][t] - mean) * rs * g1v[col] + b1v[col]);
            }
        }
        __syncthreads();   // T complete across halves
    }

    // phase-2 A fragments from T (full K; includes other half's columns)
    #pragma unroll
    for (int k = 0; k < 8; ++k)
        aReg[k] = *(const bf16x8*)&T[rowbase + c][k * 32 + quad * 8];

    #pragma unroll
    for (int t = 0; t < 8; ++t) acc[t] = (f32x4){0.f, 0.f, 0.f, 0.f};

    // ---------------- phase 2: T @ W2 (same shape) ----------------
    #pragma unroll
    for (int k = 0; k < 8; ++k) {
        if (k < 7) stageB((k + 1) & 1, W2T, (k + 1) * 32);
        const char* bb = lds + (k & 1) * 16384 + h * 8192 + roff;
        bf16x8 a = aReg[k];
        #pragma unroll
        for (int t = 0; t < 8; ++t) {
            bf16x8 b = *(const bf16x8*)(bb + t * 1024);
            acc[t] = __builtin_amdgcn_mfma_f32_16x16x32_bf16(a, b, acc[t], 0, 0, 0);
        }
        __syncthreads();
    }

    // ---------------- epilogue 2 ----------------
    if constexpr (MODE == 0) {
        short* O = (short*)Out;
        #pragma unroll
        for (int reg = 0; reg < 4; ++reg) {
            int rloc = rowbase + quad * 4 + reg; int r = bm0 + rloc;
            if (r < M) {
                float mz = mask[r] ? 0.f : 1.f;
                int n = (r >= LS_) ? 1 : 0;
                int sidx = r - n * LS_;
                #pragma unroll
                for (int t = 0; t < 8; ++t) {
                    int col = h * 128 + t * 16 + c; int hh = col >> 5, d = col & 31;
                    O[(((size_t)n * 8 + hh) * LS_ + sidx) * 32 + d] =
                        f2bf((acc[t][reg] + bias2[col]) * mz);
                }
            }
        }
    } else {
        float* O = (float*)Out;
        float vv[4][8];
        #pragma unroll
        for (int reg = 0; reg < 4; ++reg) {
            int rloc = rowbase + quad * 4 + reg;
            float s = 0.f, sq = 0.f;
            #pragma unroll
            for (int t = 0; t < 8; ++t) {
                int col = h * 128 + t * 16 + c;
                float v = gelu_exact(acc[t][reg] + bias2[col]) + bf2f(T[rloc][col]);
                vv[reg][t] = v; s += v; sq += v * v;
            }
            #pragma unroll
            for (int o = 1; o < 16; o <<= 1) {
                s += __shfl_xor(s, o, 64); sq += __shfl_xor(sq, o, 64);
            }
            if (c == 0) { PR[rloc][h][0] = s; PR[rloc][h][1] = sq; }
        }
        __syncthreads();
        #pragma unroll
        for (int reg = 0; reg < 4; ++reg) {
            int rloc = rowbase + quad * 4 + reg; int r = bm0 + rloc;
            float s  = PR[rloc][0][0] + PR[rloc][1][0];
            float sq = PR[rloc][0][1] + PR[rloc][1][1];
            float mean = s * (1.f / 256.f);
            float var  = sq * (1.f / 256.f) - mean * mean;
            float rs   = rsqrtf(var + 1e-5f);
            if (r < M) {
                #pragma unroll
                for (int t = 0; t < 8; ++t) {
                    int col = h * 128 + t * 16 + c;
                    O[(size_t)r * 256 + col] = (vv[reg][t] - mean) * rs * g2v[col] + b2v[col];
                }
            }
        }
    }
}

// ================================================================
// oa_gemm v2: S_oa = (tgt+qpos) @ [W_off|W_attn] + b   (f32 out, [ROWS,96])
// (unchanged — passed round 3)
// ================================================================
__global__ __launch_bounds__(256) void oa_gemm(
    const float* __restrict__ tgt, const float* __restrict__ qpos,
    const short* __restrict__ WToa, const float* __restrict__ b_oa,
    float* __restrict__ S_oa, int M)
{
    __shared__ __align__(16) short Bs[96][264];
    __shared__ float sb[96];

    const int tid = threadIdx.x;
    const int bm0 = blockIdx.x * 64;
    const int wave = tid >> 6, lane = tid & 63;
    const int quad = lane >> 4, c = lane & 15;

    if (tid < 96) sb[tid] = b_oa[tid];

    #pragma unroll
    for (int it = 0; it < 12; ++it) {
        int f = it * 256 + tid;
        int n = f >> 5, ko = (f & 31) * 8;
        *(int4*)&Bs[n][ko] = *(const int4*)&WToa[(size_t)n * 256 + ko];
    }

    int r = bm0 + wave * 16 + c; if (r > M - 1) r = M - 1;
    const float* At = tgt  + (size_t)r * 256 + quad * 8;
    const float* Aq = qpos + (size_t)r * 256 + quad * 8;
    bf16x8 aReg[8];
    #pragma unroll
    for (int k = 0; k < 8; ++k) {
        float4 t0 = *(const float4*)(At + k * 32);
        float4 t1 = *(const float4*)(At + k * 32 + 4);
        float4 q0 = *(const float4*)(Aq + k * 32);
        float4 q1 = *(const float4*)(Aq + k * 32 + 4);
        union { int4 i; bf16x8 v; } u;
        u.i.x = pack2bf(t0.x + q0.x, t0.y + q0.y);
        u.i.y = pack2bf(t0.z + q0.z, t0.w + q0.w);
        u.i.z = pack2bf(t1.x + q1.x, t1.y + q1.y);
        u.i.w = pack2bf(t1.z + q1.z, t1.w + q1.w);
        aReg[k] = u.v;
    }

    f32x4 acc[6];
    #pragma unroll
    for (int t = 0; t < 6; ++t) acc[t] = (f32x4){0.f, 0.f, 0.f, 0.f};

    __syncthreads();

    #pragma unroll
    for (int k = 0; k < 8; ++k) {
        bf16x8 a = aReg[k];
        #pragma unroll
        for (int t = 0; t < 6; ++t) {
            bf16x8 b = *(const bf16x8*)&Bs[t * 16 + c][k * 32 + quad * 8];
            acc[t] = __builtin_amdgcn_mfma_f32_16x16x32_bf16(a, b, acc[t], 0, 0, 0);
        }
    }

    const int rb = wave * 16 + quad * 4;
    #pragma unroll
    for (int reg = 0; reg < 4; ++reg) {
        int rr = bm0 + rb + reg;
        if (rr < M) {
            #pragma unroll
            for (int t = 0; t < 6; ++t)
                S_oa[(size_t)rr * 96 + t * 16 + c] = acc[t][reg] + sb[t * 16 + c];
        }
    }
}

// ================================================================
// deform_sample: 8 lanes per (r,h), 4 channels/lane; 7500 blocks for TLP.
// (unchanged)
// ================================================================
__global__ __launch_bounds__(256) void deform_sample(
    const short* __restrict__ value,   // [NB][8][LS_][32] bf16, head-major
    const float* __restrict__ S_oa,    // [ROWS, 96]
    const float* __restrict__ refp,    // [ROWS, 2]
    short* __restrict__ out)           // [ROWS, 256] bf16
{
    int grp = blockIdx.x * 32 + (threadIdx.x >> 3);
    int c4  = threadIdx.x & 7;
    int h = grp & 7;
    int r = grp >> 3;
    int n = (r >= LS_) ? 1 : 0;

    const float* row = S_oa + (size_t)r * 96;
    float rx = refp[(size_t)r * 2 + 0], ry = refp[(size_t)r * 2 + 1];
    float4 oA = *(const float4*)&row[h * 8];
    float4 oB = *(const float4*)&row[h * 8 + 4];
    float4 lg = *(const float4*)&row[64 + h * 4];

    float mx = fmaxf(fmaxf(lg.x, lg.y), fmaxf(lg.z, lg.w));
    float e0 = expf(lg.x - mx), e1 = expf(lg.y - mx), e2 = expf(lg.z - mx), e3 = expf(lg.w - mx);
    float inv = 1.f / (e0 + e1 + e2 + e3);
    float aw[4] = {e0 * inv, e1 * inv, e2 * inv, e3 * inv};
    float ox[4] = {oA.x, oA.z, oB.x, oB.z};
    float oy[4] = {oA.y, oA.w, oB.y, oB.w};

    const short* vb = value + (((size_t)n * 8 + h) * LS_) * 32 + c4 * 4;
    float a0 = 0.f, a1 = 0.f, a2 = 0.f, a3 = 0.f;

    #pragma unroll
    for (int p = 0; p < 4; ++p) {
        float x = rx * (float)WID + ox[p] - 0.5f;
        float y = ry * (float)HGT + oy[p] - 0.5f;
        float x0f = floorf(x), y0f = floorf(y);
        float lx = x - x0f, ly = y - y0f;
        int x0 = (int)x0f, y0 = (int)y0f;
        int x1 = x0 + 1, y1 = y0 + 1;
        bool vx0 = (x0 >= 0) & (x0 < WID), vx1 = (x1 >= 0) & (x1 < WID);
        bool vy0 = (y0 >= 0) & (y0 < HGT), vy1 = (y1 >= 0) & (y1 < HGT);
        float w00 = (vx0 & vy0) ? (1.f - lx) * (1.f - ly) * aw[p] : 0.f;
        float w10 = (vx1 & vy0) ? lx * (1.f - ly) * aw[p] : 0.f;
        float w01 = (vx0 & vy1) ? (1.f - lx) * ly * aw[p] : 0.f;
        float w11 = (vx1 & vy1) ? lx * ly * aw[p] : 0.f;
        int xc0 = min(max(x0, 0), WID - 1), xc1 = min(max(x1, 0), WID - 1);
        int yc0 = min(max(y0, 0), HGT - 1), yc1 = min(max(y1, 0), HGT - 1);
        int2 v00 = *(const int2*)&vb[(size_t)(yc0 * WID + xc0) * 32];
        int2 v10 = *(const int2*)&vb[(size_t)(yc0 * WID + xc1) * 32];
        int2 v01 = *(const int2*)&vb[(size_t)(yc1 * WID + xc0) * 32];
        int2 v11 = *(const int2*)&vb[(size_t)(yc1 * WID + xc1) * 32];
        a0 += w00 * __uint_as_float(((unsigned)v00.x) << 16)
            + w10 * __uint_as_float(((unsigned)v10.x) << 16)
            + w01 * __uint_as_float(((unsigned)v01.x) << 16)
            + w11 * __uint_as_float(((unsigned)v11.x) << 16);
        a1 += w00 * __uint_as_float(v00.x & 0xffff0000u)
            + w10 * __uint_as_float(v10.x & 0xffff0000u)
            + w01 * __uint_as_float(v01.x & 0xffff0000u)
            + w11 * __uint_as_float(v11.x & 0xffff0000u);
        a2 += w00 * __uint_as_float(((unsigned)v00.y) << 16)
            + w10 * __uint_as_float(((unsigned)v10.y) << 16)
            + w01 * __uint_as_float(((unsigned)v01.y) << 16)
            + w11 * __uint_as_float(((unsigned)v11.y) << 16);
        a3 += w00 * __uint_as_float(v00.y & 0xffff0000u)
            + w10 * __uint_as_float(v10.y & 0xffff0000u)
            + w01 * __uint_as_float(v01.y & 0xffff0000u)
            + w11 * __uint_as_float(v11.y & 0xffff0000u);
    }
    int2 o;
    o.x = pack2bf(a0, a1);
    o.y = pack2bf(a2, a3);
    *(int2*)&out[(size_t)r * 256 + h * 32 + c4 * 4] = o;
}

// ================================================================
// prep_all: all weight prep in one dispatch (401 blocks)  (unchanged)
// ================================================================
__global__ __launch_bounds__(256) void prep_all(
    const float* __restrict__ W_dsa, const float* __restrict__ W_val,
    const float* __restrict__ W_ff,  const float* __restrict__ W_out,
    const float* __restrict__ W_csa, const float* __restrict__ b_out,
    const float* __restrict__ b_csa, const float* __restrict__ W_off,
    const float* __restrict__ W_attn, const float* __restrict__ b_off,
    const float* __restrict__ b_attn,
    short* __restrict__ WT_dsa, short* __restrict__ WT_val, short* __restrict__ WT_ff,
    short* __restrict__ WT_c, float* __restrict__ bc,
    short* __restrict__ WT_oa, float* __restrict__ b_oa)
{
    __shared__ float tile[64][65];
    const int b = blockIdx.x, tid = threadIdx.x;
    if (b < 48) {
        const float* W = (b < 16) ? W_dsa : (b < 32) ? W_val : W_ff;
        short* WT = (b < 16) ? WT_dsa : (b < 32) ? WT_val : WT_ff;
        int t = b & 15; int bx = (t & 3) * 64, by = (t >> 2) * 64;
        #pragma unroll
        for (int it = 0; it < 4; ++it) {
            int f = it * 256 + tid; int i = f >> 4; int j = (f & 15) * 4;
            float4 v = *(const float4*)&W[(size_t)(by + i) * 256 + bx + j];
            tile[i][j] = v.x; tile[i][j + 1] = v.y; tile[i][j + 2] = v.z; tile[i][j + 3] = v.w;
        }
        __syncthreads();
        #pragma unroll
        for (int it = 0; it < 16; ++it) {
            int f = it * 256 + tid; int nl = f >> 6; int kl = f & 63;
            WT[(size_t)(bx + nl) * 256 + by + kl] = f2bf(tile[kl][nl]);
        }
    } else if (b < 304) {
        int k = b - 48, n = tid;
        float s = 0.f;
        #pragma unroll 8
        for (int j = 0; j < 256; ++j)
            s = fmaf(W_out[(size_t)k * 256 + j], W_csa[(size_t)j * 256 + n], s);
        WT_c[(size_t)n * 256 + k] = f2bf(s);
    } else if (b == 304) {
        int j = tid;
        float s = b_csa[j];
        #pragma unroll 8
        for (int k = 0; k < 256; ++k)
            s = fmaf(b_out[k], W_csa[(size_t)k * 256 + j], s);
        bc[j] = s;
    } else {
        int j = b - 305, k = tid;
        float v = (j < 64) ? W_off[(size_t)k * 64 + j] : W_attn[(size_t)k * 32 + (j - 64)];
        WT_oa[(size_t)j * 256 + k] = f2bf(v);
        if (k == 0) b_oa[j] = (j < 64) ? b_off[j] : b_attn[j - 64];
    }
}

// ================= launcher =================
extern "C" void kernel_launch(void* const* d_in, const int* in_sizes, int n_in,
                              void* d_out, int out_size, void* d_ws, size_t ws_size,
                              hipStream_t stream)
{
    const float* tgt       = (const float*)d_in[0];
    const float* query_pos = (const float*)d_in[1];
    const float* refp      = (const float*)d_in[4];
    const float* src       = (const float*)d_in[6];
    const unsigned char* mask = (const unsigned char*)d_in[9];
    const float* W_dsa  = (const float*)d_in[10]; const float* b_dsa  = (const float*)d_in[11];
    const float* g_nds  = (const float*)d_in[12]; const float* b_nds  = (const float*)d_in[13];
    const float* W_off  = (const float*)d_in[14]; const float* b_off  = (const float*)d_in[15];
    const float* W_attn = (const float*)d_in[16]; const float* b_attn = (const float*)d_in[17];
    const float* W_val  = (const float*)d_in[18]; const float* b_val  = (const float*)d_in[19];
    const float* W_out  = (const float*)d_in[20]; const float* b_out  = (const float*)d_in[21];
    const float* W_csa  = (const float*)d_in[22]; const float* b_csa  = (const float*)d_in[23];
    const float* g_n1   = (const float*)d_in[24]; const float* b_n1   = (const float*)d_in[25];
    const float* W_ff   = (const float*)d_in[26]; const float* b_ff   = (const float*)d_in[27];
    const float* g_n3   = (const float*)d_in[28]; const float* b_n3   = (const float*)d_in[29];
    float* out = (float*)d_out;

    short* attn_out = (short*)d_ws;                       // [30000*256] bf16
    short* value    = attn_out + (size_t)ROWS * 256;      // [30000*256] bf16 head-major
    float* S_oa     = (float*)(value + (size_t)ROWS * 256); // [30000*96] f32
    short* WT_dsa   = (short*)(S_oa + (size_t)ROWS * 96);
    short* WT_val   = WT_dsa + 65536;
    short* WT_ff    = WT_val + 65536;
    short* WT_c     = WT_ff + 65536;
    short* WT_oa    = WT_c + 65536;                       // 96*256
    float* bc       = (float*)(WT_oa + 96 * 256);
    float* b_oa     = bc + 256;

    dim3 blk(256), blk2(512);
    const int GB = (ROWS + 63) / 64;   // 469

    prep_all<<<401, blk, 0, stream>>>(
        W_dsa, W_val, W_ff, W_out, W_csa, b_out, b_csa, W_off, W_attn, b_off, b_attn,
        WT_dsa, WT_val, WT_ff, WT_c, bc, WT_oa, b_oa);

    // S_oa = (tgt+qpos)@[W_off|W_attn]+b  (independent of value path)
    oa_gemm<<<GB, blk, 0, stream>>>(tgt, query_pos, WT_oa, b_oa, S_oa, ROWS);

    // value = mask(LN(src@W_dsa+b_dsa) @ W_val + b_val), head-major
    fused2<0><<<GB, blk2, 0, stream>>>(
        src, WT_dsa, b_dsa, nullptr, g_nds, b_nds,
        WT_val, b_val, value, mask, nullptr, nullptr, ROWS);

    // attn_out = deform-sample (softmax fused), high-TLP grid
    deform_sample<<<ROWS * 8 / 32, blk, 0, stream>>>(value, S_oa, refp, attn_out);

    // out = LN3(t + gelu(t@W_ff+b_ff)), t = LN1(tgt + attn_out@Wc+bc)
    fused2<1><<<GB, blk2, 0, stream>>>(
        attn_out, WT_c, bc, tgt, g_n1, b_n1,
        WT_ff, b_ff, out, nullptr, g_n3, b_n3, ROWS);
}